// Round 1
// baseline (1189.495 us; speedup 1.0000x reference)
//
#include <hip/hip_runtime.h>
#include <math.h>

#define NN 50000
#define EE 800000
#define FIN 128
#define HID 96
#define NL 4
#define CHUNK 1024

__device__ __forceinline__ float wave_sum(float v) {
    #pragma unroll
    for (int off = 32; off > 0; off >>= 1) v += __shfl_xor(v, off);
    return v;
}

// ---------------- CSR build ----------------
__global__ void k_hist(const int* __restrict__ dst, int* __restrict__ deg, int E) {
    int e = blockIdx.x * blockDim.x + threadIdx.x;
    if (e < E) atomicAdd(&deg[dst[e]], 1);
}

__global__ void k_scan1(const int* __restrict__ deg, int* __restrict__ partials, int n) {
    __shared__ int lds[256];
    int t = threadIdx.x;
    int base = blockIdx.x * CHUNK + t * 4;
    int s = 0;
    #pragma unroll
    for (int q = 0; q < 4; q++) { int idx = base + q; if (idx < n) s += deg[idx]; }
    lds[t] = s; __syncthreads();
    for (int o = 128; o > 0; o >>= 1) { if (t < o) lds[t] += lds[t + o]; __syncthreads(); }
    if (t == 0) partials[blockIdx.x] = lds[0];
}

__global__ void k_scan_mid(int* partials, int nb, int* rowptr, int n) {
    int run = 0;
    for (int i = 0; i < nb; i++) { int v = partials[i]; partials[i] = run; run += v; }
    rowptr[n] = run;
}

__global__ void k_scan3(const int* __restrict__ deg, const int* __restrict__ partials,
                        int* __restrict__ rowptr, int* __restrict__ cursor, int n) {
    __shared__ int lds[256];
    int t = threadIdx.x;
    int base = blockIdx.x * CHUNK + t * 4;
    int v[4];
    #pragma unroll
    for (int q = 0; q < 4; q++) { int idx = base + q; v[q] = (idx < n) ? deg[idx] : 0; }
    int tsum = v[0] + v[1] + v[2] + v[3];
    lds[t] = tsum; __syncthreads();
    for (int o = 1; o < 256; o <<= 1) {
        int add = (t >= o) ? lds[t - o] : 0;
        __syncthreads();
        lds[t] += add;
        __syncthreads();
    }
    int excl = lds[t] - tsum;
    int run = partials[blockIdx.x] + excl;
    #pragma unroll
    for (int q = 0; q < 4; q++) {
        int idx = base + q;
        if (idx < n) { rowptr[idx] = run; cursor[idx] = run; run += v[q]; }
    }
}

__global__ void k_scatter(const int* __restrict__ dst, int* __restrict__ cursor,
                          int* __restrict__ eidx, int E) {
    int e = blockIdx.x * blockDim.x + threadIdx.x;
    if (e < E) { int p = atomicAdd(&cursor[dst[e]], 1); eidx[p] = e; }
}

// ---------------- encoder GEMM: h = x @ W + b  (K=128 -> 96) ----------------
__global__ __launch_bounds__(192) void k_enc(const float* __restrict__ x, const float* __restrict__ W,
                                             const float* __restrict__ b, float* __restrict__ h, int n) {
    __shared__ float xs[16 * FIN];
    int i0 = blockIdx.x * 16;
    for (int idx = threadIdx.x; idx < 16 * FIN; idx += 192) {
        int row = i0 + idx / FIN;
        xs[idx] = (row < n) ? x[(size_t)i0 * FIN + idx] : 0.f;
    }
    __syncthreads();
    int j = threadIdx.x % 96;
    int g = threadIdx.x / 96;
    float acc[8];
    #pragma unroll
    for (int r = 0; r < 8; r++) acc[r] = 0.f;
    #pragma unroll 4
    for (int k = 0; k < FIN; k++) {
        float w = W[k * 96 + j];
        #pragma unroll
        for (int r = 0; r < 8; r++) acc[r] = fmaf(xs[(g * 8 + r) * FIN + k], w, acc[r]);
    }
    float bj = b[j];
    #pragma unroll
    for (int r = 0; r < 8; r++) {
        int row = i0 + g * 8 + r;
        if (row < n) h[(size_t)row * HID + j] = acc[r] + bj;
    }
}

// ---------------- layer GEMMs: xl = hn@Wl+bl, xr = hn@Wr+br ----------------
__global__ __launch_bounds__(192) void k_gemm2(const float* __restrict__ hn,
        const float* __restrict__ Wl, const float* __restrict__ bl,
        const float* __restrict__ Wr, const float* __restrict__ br,
        float* __restrict__ xl, float* __restrict__ xr, int n) {
    __shared__ float hs[16 * HID];
    int i0 = blockIdx.x * 16;
    for (int idx = threadIdx.x; idx < 16 * HID; idx += 192) {
        int row = i0 + idx / HID;
        hs[idx] = (row < n) ? hn[(size_t)i0 * HID + idx] : 0.f;
    }
    __syncthreads();
    int j = threadIdx.x % 96;
    int g = threadIdx.x / 96;
    float accl[8], accr[8];
    #pragma unroll
    for (int r = 0; r < 8; r++) { accl[r] = 0.f; accr[r] = 0.f; }
    #pragma unroll 4
    for (int k = 0; k < HID; k++) {
        float wl = Wl[k * 96 + j];
        float wr = Wr[k * 96 + j];
        #pragma unroll
        for (int r = 0; r < 8; r++) {
            float hv = hs[(g * 8 + r) * HID + k];
            accl[r] = fmaf(hv, wl, accl[r]);
            accr[r] = fmaf(hv, wr, accr[r]);
        }
    }
    float bjl = bl[j], bjr = br[j];
    #pragma unroll
    for (int r = 0; r < 8; r++) {
        int row = i0 + g * 8 + r;
        if (row < n) {
            xl[(size_t)row * HID + j] = accl[r] + bjl;
            xr[(size_t)row * HID + j] = accr[r] + bjr;
        }
    }
}

// ---------------- LN + relu (wave per node) ----------------
__global__ __launch_bounds__(256) void k_ln_relu(const float* __restrict__ h, const float* __restrict__ g,
                                                 const float* __restrict__ bt, float* __restrict__ hn, int n) {
    int lane = threadIdx.x & 63;
    int node = blockIdx.x * 4 + (threadIdx.x >> 6);
    if (node >= n) return;
    const float* row = h + (size_t)node * HID;
    float x0 = row[lane];
    float x1 = (lane < 32) ? row[64 + lane] : 0.f;
    float s  = wave_sum(x0 + x1);
    float sq = wave_sum(x0 * x0 + x1 * x1);
    float mu = s * (1.f / 96.f);
    float var = sq * (1.f / 96.f) - mu * mu;
    float rs = rsqrtf(var + 1e-5f);
    float y0 = (x0 - mu) * rs * g[lane] + bt[lane];
    hn[(size_t)node * HID + lane] = fmaxf(y0, 0.f);
    if (lane < 32) {
        float y1 = (x1 - mu) * rs * g[64 + lane] + bt[64 + lane];
        hn[(size_t)node * HID + 64 + lane] = fmaxf(y1, 0.f);
    }
}

// ---------------- fused GATv2 edge-score + online-softmax + aggregate + residual ----------------
__global__ __launch_bounds__(256) void k_gat(const float* __restrict__ xl, const float* __restrict__ xr,
        const int* __restrict__ src, const float* __restrict__ ew,
        const int* __restrict__ rowptr, const int* __restrict__ eidx,
        const float* __restrict__ We, const float* __restrict__ att, const float* __restrict__ bias,
        float* __restrict__ h, int n) {
    int lane = threadIdx.x & 63;
    int node = blockIdx.x * 4 + (threadIdx.x >> 6);
    if (node >= n) return;
    bool hi = lane < 32;
    float we0 = We[lane],               at0 = att[lane];
    float we1 = hi ? We[64 + lane] : 0.f, at1 = hi ? att[64 + lane] : 0.f;
    const float* xrr = xr + (size_t)node * HID;
    float xr0 = xrr[lane];
    float xr1 = hi ? xrr[64 + lane] : 0.f;
    int beg = rowptr[node], end = rowptr[node + 1];
    float m = -INFINITY, ssum = 0.f, acc0 = 0.f, acc1 = 0.f;
    for (int p = beg; p < end; p++) {
        int e = eidx[p];
        int se = src[e];
        float w = ew[e];
        const float* xlr = xl + (size_t)se * HID;
        float v0 = xlr[lane];
        float v1 = hi ? xlr[64 + lane] : 0.f;
        float t0 = v0 + xr0 + w * we0;
        t0 = (t0 > 0.f ? t0 : 0.2f * t0) * at0;
        float t1 = v1 + xr1 + w * we1;
        t1 = (t1 > 0.f ? t1 : 0.2f * t1) * at1;   // lanes>=32: all-zero inputs -> 0
        float alpha = wave_sum(t0 + t1);
        float mn = fmaxf(m, alpha);
        float sc = __expf(m - mn);       // first iter: exp(-inf)=0
        float wx = __expf(alpha - mn);
        ssum = ssum * sc + wx;
        acc0 = acc0 * sc + wx * v0;
        acc1 = acc1 * sc + wx * v1;
        m = mn;
    }
    float inv = 1.f / (ssum + 1e-16f);
    h[(size_t)node * HID + lane] += acc0 * inv + bias[lane];
    if (hi) h[(size_t)node * HID + 64 + lane] += acc1 * inv + bias[64 + lane];
}

// ---------------- final LN + relu + fc ----------------
__global__ __launch_bounds__(256) void k_final(const float* __restrict__ h, const float* __restrict__ g,
        const float* __restrict__ bt, const float* __restrict__ fcW, const float* __restrict__ fcb,
        float* __restrict__ out, int n) {
    int lane = threadIdx.x & 63;
    int node = blockIdx.x * 4 + (threadIdx.x >> 6);
    if (node >= n) return;
    const float* row = h + (size_t)node * HID;
    float x0 = row[lane];
    float x1 = (lane < 32) ? row[64 + lane] : 0.f;
    float s  = wave_sum(x0 + x1);
    float sq = wave_sum(x0 * x0 + x1 * x1);
    float mu = s * (1.f / 96.f);
    float var = sq * (1.f / 96.f) - mu * mu;
    float rs = rsqrtf(var + 1e-5f);
    float y0 = fmaxf((x0 - mu) * rs * g[lane] + bt[lane], 0.f);
    float p = y0 * fcW[lane];
    if (lane < 32) {
        float y1 = fmaxf((x1 - mu) * rs * g[64 + lane] + bt[64 + lane], 0.f);
        p += y1 * fcW[64 + lane];
    }
    p = wave_sum(p);
    if (lane == 0) out[node] = p + fcb[0];
}

extern "C" void kernel_launch(void* const* d_in, const int* in_sizes, int n_in,
                              void* d_out, int out_size, void* d_ws, size_t ws_size,
                              hipStream_t stream) {
    const float* x    = (const float*)d_in[0];
    const int*   ei   = (const int*)  d_in[1];
    const float* ew   = (const float*)d_in[2];
    const float* encW = (const float*)d_in[3];
    const float* encB = (const float*)d_in[4];
    const float* Wl   = (const float*)d_in[5];
    const float* bl   = (const float*)d_in[6];
    const float* Wr   = (const float*)d_in[7];
    const float* br   = (const float*)d_in[8];
    const float* We   = (const float*)d_in[9];
    const float* att  = (const float*)d_in[10];
    const float* bias = (const float*)d_in[11];
    const float* lng  = (const float*)d_in[12];
    const float* lnb  = (const float*)d_in[13];
    const float* lnfg = (const float*)d_in[14];
    const float* lnfb = (const float*)d_in[15];
    const float* fcW  = (const float*)d_in[16];
    const float* fcb  = (const float*)d_in[17];
    float* out = (float*)d_out;

    const int* src = ei;
    const int* dst = ei + EE;

    char* ws = (char*)d_ws;
    size_t off = 0;
    auto alloc = [&](size_t bytes) -> void* {
        void* p = ws + off;
        off += (bytes + 255) & ~(size_t)255;
        return p;
    };
    float* h      = (float*)alloc((size_t)NN * HID * 4);
    float* hn     = (float*)alloc((size_t)NN * HID * 4);
    float* xl     = (float*)alloc((size_t)NN * HID * 4);
    float* xr     = (float*)alloc((size_t)NN * HID * 4);
    int*   deg    = (int*)  alloc((size_t)NN * 4);
    int*   rowptr = (int*)  alloc((size_t)(NN + 1) * 4);
    int*   cursor = (int*)  alloc((size_t)NN * 4);
    int*   eidx   = (int*)  alloc((size_t)EE * 4);
    int*   parts  = (int*)  alloc(256 * 4);

    const int NB = (NN + CHUNK - 1) / CHUNK;   // 49
    const int EB = (EE + 255) / 256;           // 3125
    const int GB = (NN + 15) / 16;             // 3125
    const int WB = (NN + 3) / 4;               // 12500

    // CSR build (edges identical across layers -> build once per call)
    hipMemsetAsync(deg, 0, (size_t)NN * 4, stream);
    k_hist<<<EB, 256, 0, stream>>>(dst, deg, EE);
    k_scan1<<<NB, 256, 0, stream>>>(deg, parts, NN);
    k_scan_mid<<<1, 1, 0, stream>>>(parts, NB, rowptr, NN);
    k_scan3<<<NB, 256, 0, stream>>>(deg, parts, rowptr, cursor, NN);
    k_scatter<<<EB, 256, 0, stream>>>(dst, cursor, eidx, EE);

    // encoder
    k_enc<<<GB, 192, 0, stream>>>(x, encW, encB, h, NN);

    for (int l = 0; l < NL; l++) {
        k_ln_relu<<<WB, 256, 0, stream>>>(h, lng + l * HID, lnb + l * HID, hn, NN);
        k_gemm2<<<GB, 192, 0, stream>>>(hn, Wl + l * HID * HID, bl + l * HID,
                                        Wr + l * HID * HID, br + l * HID, xl, xr, NN);
        k_gat<<<WB, 256, 0, stream>>>(xl, xr, src, ew, rowptr, eidx,
                                      We + l * HID, att + l * HID, bias + l * HID, h, NN);
    }

    k_final<<<WB, 256, 0, stream>>>(h, lnfg, lnfb, fcW, fcb, out, NN);
}

// Round 2
// 821.487 us; speedup vs baseline: 1.4480x; 1.4480x over previous
//
#include <hip/hip_runtime.h>
#include <math.h>

#define NN 50000
#define EE 800000
#define FIN 128
#define HID 96
#define NL 4
#define CHUNK 1024

__device__ __forceinline__ float wave_sum(float v) {
    #pragma unroll
    for (int off = 32; off > 0; off >>= 1) v += __shfl_xor(v, off);
    return v;
}

// ---------------- CSR build ----------------
__global__ void k_hist(const int* __restrict__ dst, int* __restrict__ deg, int E) {
    int e = blockIdx.x * blockDim.x + threadIdx.x;
    if (e < E) atomicAdd(&deg[dst[e]], 1);
}

__global__ void k_scan1(const int* __restrict__ deg, int* __restrict__ partials, int n) {
    __shared__ int lds[256];
    int t = threadIdx.x;
    int base = blockIdx.x * CHUNK + t * 4;
    int s = 0;
    #pragma unroll
    for (int q = 0; q < 4; q++) { int idx = base + q; if (idx < n) s += deg[idx]; }
    lds[t] = s; __syncthreads();
    for (int o = 128; o > 0; o >>= 1) { if (t < o) lds[t] += lds[t + o]; __syncthreads(); }
    if (t == 0) partials[blockIdx.x] = lds[0];
}

__global__ void k_scan_mid(int* partials, int nb, int* rowptr, int n) {
    int run = 0;
    for (int i = 0; i < nb; i++) { int v = partials[i]; partials[i] = run; run += v; }
    rowptr[n] = run;
}

__global__ void k_scan3(const int* __restrict__ deg, const int* __restrict__ partials,
                        int* __restrict__ rowptr, int* __restrict__ cursor, int n) {
    __shared__ int lds[256];
    int t = threadIdx.x;
    int base = blockIdx.x * CHUNK + t * 4;
    int v[4];
    #pragma unroll
    for (int q = 0; q < 4; q++) { int idx = base + q; v[q] = (idx < n) ? deg[idx] : 0; }
    int tsum = v[0] + v[1] + v[2] + v[3];
    lds[t] = tsum; __syncthreads();
    for (int o = 1; o < 256; o <<= 1) {
        int add = (t >= o) ? lds[t - o] : 0;
        __syncthreads();
        lds[t] += add;
        __syncthreads();
    }
    int excl = lds[t] - tsum;
    int run = partials[blockIdx.x] + excl;
    #pragma unroll
    for (int q = 0; q < 4; q++) {
        int idx = base + q;
        if (idx < n) { rowptr[idx] = run; cursor[idx] = run; run += v[q]; }
    }
}

// scatter edges into CSR order, reordering (src, ew) payloads to kill one indirection
__global__ void k_scatter(const int* __restrict__ src, const int* __restrict__ dst,
                          const float* __restrict__ ew, int* __restrict__ cursor,
                          int* __restrict__ srcs_o, float* __restrict__ ews_o, int E) {
    int e = blockIdx.x * blockDim.x + threadIdx.x;
    if (e < E) {
        int p = atomicAdd(&cursor[dst[e]], 1);
        srcs_o[p] = src[e];
        ews_o[p]  = ew[e];
    }
}

// ---------------- encoder GEMM: h = x @ W + b  (50000x128 @ 128x96) ----------------
// block: 192 threads = 24 col-groups x 8 row-groups; thread tile 4 rows x 4 cols; M=32/block
__global__ __launch_bounds__(192) void k_enc(const float* __restrict__ x, const float* __restrict__ W,
                                             const float* __restrict__ b, float* __restrict__ h, int n) {
    __shared__ float xs[32 * 129];   // [row][k], stride 129 (bank-spread b32 reads)
    __shared__ float ws[32 * 100];   // [kk][col], stride 100 (b128-aligned)
    int t = threadIdx.x;
    int i0 = blockIdx.x * 32;
    // stage x tile (full K=128)
    for (int u = t; u < 32 * 32; u += 192) {
        int r = u >> 5, q = u & 31;
        int row = i0 + r;
        float4 v = make_float4(0.f, 0.f, 0.f, 0.f);
        if (row < n) v = *(const float4*)(x + (size_t)row * FIN + 4 * q);
        float* d = xs + r * 129 + 4 * q;
        d[0] = v.x; d[1] = v.y; d[2] = v.z; d[3] = v.w;
    }
    int cg = t % 24, rg = t / 24;
    int c0 = 4 * cg, r0 = 4 * rg;
    float acc[4][4];
    #pragma unroll
    for (int i = 0; i < 4; i++)
        #pragma unroll
        for (int j = 0; j < 4; j++) acc[i][j] = 0.f;
    for (int kt = 0; kt < FIN; kt += 32) {
        __syncthreads();
        for (int u = t; u < 32 * 24; u += 192) {
            int kk = u / 24, q = u % 24;
            float4 v = *(const float4*)(W + (size_t)(kt + kk) * 96 + 4 * q);
            float* d = ws + kk * 100 + 4 * q;
            d[0] = v.x; d[1] = v.y; d[2] = v.z; d[3] = v.w;
        }
        __syncthreads();
        #pragma unroll 8
        for (int kk = 0; kk < 32; kk++) {
            float hv[4];
            #pragma unroll
            for (int i = 0; i < 4; i++) hv[i] = xs[(r0 + i) * 129 + kt + kk];
            float4 w4 = *(const float4*)(ws + kk * 100 + c0);
            #pragma unroll
            for (int i = 0; i < 4; i++) {
                acc[i][0] = fmaf(hv[i], w4.x, acc[i][0]);
                acc[i][1] = fmaf(hv[i], w4.y, acc[i][1]);
                acc[i][2] = fmaf(hv[i], w4.z, acc[i][2]);
                acc[i][3] = fmaf(hv[i], w4.w, acc[i][3]);
            }
        }
    }
    float4 b4 = *(const float4*)(b + c0);
    #pragma unroll
    for (int i = 0; i < 4; i++) {
        int row = i0 + r0 + i;
        if (row < n) {
            float4 o = make_float4(acc[i][0] + b4.x, acc[i][1] + b4.y,
                                   acc[i][2] + b4.z, acc[i][3] + b4.w);
            *(float4*)(h + (size_t)row * HID + c0) = o;
        }
    }
}

// ---------------- layer GEMMs: xl = hn@Wl+bl, xr = hn@Wr+br ----------------
__global__ __launch_bounds__(192) void k_gemm2(const float* __restrict__ hn,
        const float* __restrict__ Wl, const float* __restrict__ bl,
        const float* __restrict__ Wr, const float* __restrict__ br,
        float* __restrict__ xl, float* __restrict__ xr, int n) {
    __shared__ float hs[32 * 97];
    __shared__ float wsl[32 * 100];
    __shared__ float wsr[32 * 100];
    int t = threadIdx.x;
    int i0 = blockIdx.x * 32;
    for (int u = t; u < 32 * 24; u += 192) {
        int r = u / 24, q = u % 24;
        int row = i0 + r;
        float4 v = make_float4(0.f, 0.f, 0.f, 0.f);
        if (row < n) v = *(const float4*)(hn + (size_t)row * HID + 4 * q);
        float* d = hs + r * 97 + 4 * q;
        d[0] = v.x; d[1] = v.y; d[2] = v.z; d[3] = v.w;
    }
    int cg = t % 24, rg = t / 24;
    int c0 = 4 * cg, r0 = 4 * rg;
    float accl[4][4], accr[4][4];
    #pragma unroll
    for (int i = 0; i < 4; i++)
        #pragma unroll
        for (int j = 0; j < 4; j++) { accl[i][j] = 0.f; accr[i][j] = 0.f; }
    for (int kt = 0; kt < HID; kt += 32) {
        __syncthreads();
        for (int u = t; u < 32 * 24; u += 192) {
            int kk = u / 24, q = u % 24;
            float4 vl = *(const float4*)(Wl + (size_t)(kt + kk) * 96 + 4 * q);
            float4 vr = *(const float4*)(Wr + (size_t)(kt + kk) * 96 + 4 * q);
            float* dl = wsl + kk * 100 + 4 * q;
            float* dr = wsr + kk * 100 + 4 * q;
            dl[0] = vl.x; dl[1] = vl.y; dl[2] = vl.z; dl[3] = vl.w;
            dr[0] = vr.x; dr[1] = vr.y; dr[2] = vr.z; dr[3] = vr.w;
        }
        __syncthreads();
        #pragma unroll 4
        for (int kk = 0; kk < 32; kk++) {
            float hv[4];
            #pragma unroll
            for (int i = 0; i < 4; i++) hv[i] = hs[(r0 + i) * 97 + kt + kk];
            float4 wl4 = *(const float4*)(wsl + kk * 100 + c0);
            float4 wr4 = *(const float4*)(wsr + kk * 100 + c0);
            #pragma unroll
            for (int i = 0; i < 4; i++) {
                accl[i][0] = fmaf(hv[i], wl4.x, accl[i][0]);
                accl[i][1] = fmaf(hv[i], wl4.y, accl[i][1]);
                accl[i][2] = fmaf(hv[i], wl4.z, accl[i][2]);
                accl[i][3] = fmaf(hv[i], wl4.w, accl[i][3]);
                accr[i][0] = fmaf(hv[i], wr4.x, accr[i][0]);
                accr[i][1] = fmaf(hv[i], wr4.y, accr[i][1]);
                accr[i][2] = fmaf(hv[i], wr4.z, accr[i][2]);
                accr[i][3] = fmaf(hv[i], wr4.w, accr[i][3]);
            }
        }
    }
    float4 bl4 = *(const float4*)(bl + c0);
    float4 br4 = *(const float4*)(br + c0);
    #pragma unroll
    for (int i = 0; i < 4; i++) {
        int row = i0 + r0 + i;
        if (row < n) {
            float4 ol = make_float4(accl[i][0] + bl4.x, accl[i][1] + bl4.y,
                                    accl[i][2] + bl4.z, accl[i][3] + bl4.w);
            float4 orr = make_float4(accr[i][0] + br4.x, accr[i][1] + br4.y,
                                     accr[i][2] + br4.z, accr[i][3] + br4.w);
            *(float4*)(xl + (size_t)row * HID + c0) = ol;
            *(float4*)(xr + (size_t)row * HID + c0) = orr;
        }
    }
}

// ---------------- LN + relu (wave per node, float2 lanes<48) ----------------
__global__ __launch_bounds__(256) void k_ln_relu(const float* __restrict__ h, const float* __restrict__ g,
                                                 const float* __restrict__ bt, float* __restrict__ hn, int n) {
    int lane = threadIdx.x & 63;
    int node = blockIdx.x * 4 + (threadIdx.x >> 6);
    if (node >= n) return;
    bool act = lane < 48;
    int d = lane * 2;
    float2 x2 = make_float2(0.f, 0.f);
    if (act) x2 = *(const float2*)(h + (size_t)node * HID + d);
    float s  = wave_sum(x2.x + x2.y);
    float sq = wave_sum(x2.x * x2.x + x2.y * x2.y);
    float mu = s * (1.f / 96.f);
    float var = sq * (1.f / 96.f) - mu * mu;
    float rs = rsqrtf(var + 1e-5f);
    if (act) {
        float2 g2 = *(const float2*)(g + d);
        float2 b2 = *(const float2*)(bt + d);
        float2 o;
        o.x = fmaxf((x2.x - mu) * rs * g2.x + b2.x, 0.f);
        o.y = fmaxf((x2.y - mu) * rs * g2.y + b2.y, 0.f);
        *(float2*)(hn + (size_t)node * HID + d) = o;
    }
}

// ---------------- fused GATv2: score + online-softmax + aggregate + residual ----------------
__global__ __launch_bounds__(256) void k_gat(const float* __restrict__ xl, const float* __restrict__ xr,
        const int* __restrict__ srcs, const float* __restrict__ ews,
        const int* __restrict__ rowptr,
        const float* __restrict__ We, const float* __restrict__ att, const float* __restrict__ bias,
        float* __restrict__ h, int n) {
    int lane = threadIdx.x & 63;
    int node = blockIdx.x * 4 + (threadIdx.x >> 6);
    if (node >= n) return;
    bool act = lane < 48;
    int d = lane * 2;
    float2 we2 = make_float2(0.f, 0.f), at2 = make_float2(0.f, 0.f), xr2 = make_float2(0.f, 0.f);
    if (act) {
        we2 = *(const float2*)(We + d);
        at2 = *(const float2*)(att + d);
        xr2 = *(const float2*)(xr + (size_t)node * HID + d);
    }
    int beg = rowptr[node], end = rowptr[node + 1];
    float m = -INFINITY, ssum = 0.f, ax = 0.f, ay = 0.f;
    int p = beg;
    for (; p + 1 < end; p += 2) {
        int s0 = srcs[p], s1 = srcs[p + 1];
        float w0 = ews[p], w1 = ews[p + 1];
        float2 v0 = make_float2(0.f, 0.f), v1 = make_float2(0.f, 0.f);
        if (act) {
            v0 = *(const float2*)(xl + (size_t)s0 * HID + d);
            v1 = *(const float2*)(xl + (size_t)s1 * HID + d);
        }
        float t0x = v0.x + xr2.x + w0 * we2.x; t0x = (t0x > 0.f ? t0x : 0.2f * t0x);
        float t0y = v0.y + xr2.y + w0 * we2.y; t0y = (t0y > 0.f ? t0y : 0.2f * t0y);
        float t1x = v1.x + xr2.x + w1 * we2.x; t1x = (t1x > 0.f ? t1x : 0.2f * t1x);
        float t1y = v1.y + xr2.y + w1 * we2.y; t1y = (t1y > 0.f ? t1y : 0.2f * t1y);
        float q0 = t0x * at2.x + t0y * at2.y;
        float q1 = t1x * at2.x + t1y * at2.y;
        #pragma unroll
        for (int off = 32; off > 0; off >>= 1) {
            q0 += __shfl_xor(q0, off);
            q1 += __shfl_xor(q1, off);
        }
        float mn = fmaxf(m, fmaxf(q0, q1));
        float sc = __expf(m - mn);
        float e0 = __expf(q0 - mn);
        float e1 = __expf(q1 - mn);
        ssum = ssum * sc + e0 + e1;
        ax = ax * sc + e0 * v0.x + e1 * v1.x;
        ay = ay * sc + e0 * v0.y + e1 * v1.y;
        m = mn;
    }
    if (p < end) {
        int s0 = srcs[p];
        float w0 = ews[p];
        float2 v0 = make_float2(0.f, 0.f);
        if (act) v0 = *(const float2*)(xl + (size_t)s0 * HID + d);
        float t0x = v0.x + xr2.x + w0 * we2.x; t0x = (t0x > 0.f ? t0x : 0.2f * t0x);
        float t0y = v0.y + xr2.y + w0 * we2.y; t0y = (t0y > 0.f ? t0y : 0.2f * t0y);
        float q0 = wave_sum(t0x * at2.x + t0y * at2.y);
        float mn = fmaxf(m, q0);
        float sc = __expf(m - mn);
        float e0 = __expf(q0 - mn);
        ssum = ssum * sc + e0;
        ax = ax * sc + e0 * v0.x;
        ay = ay * sc + e0 * v0.y;
        m = mn;
    }
    float inv = 1.f / (ssum + 1e-16f);
    if (act) {
        float2 b2 = *(const float2*)(bias + d);
        float* hp = h + (size_t)node * HID + d;
        float2 hv = *(float2*)hp;
        hv.x += ax * inv + b2.x;
        hv.y += ay * inv + b2.y;
        *(float2*)hp = hv;
    }
}

// ---------------- final LN + relu + fc ----------------
__global__ __launch_bounds__(256) void k_final(const float* __restrict__ h, const float* __restrict__ g,
        const float* __restrict__ bt, const float* __restrict__ fcW, const float* __restrict__ fcb,
        float* __restrict__ out, int n) {
    int lane = threadIdx.x & 63;
    int node = blockIdx.x * 4 + (threadIdx.x >> 6);
    if (node >= n) return;
    bool act = lane < 48;
    int d = lane * 2;
    float2 x2 = make_float2(0.f, 0.f);
    if (act) x2 = *(const float2*)(h + (size_t)node * HID + d);
    float s  = wave_sum(x2.x + x2.y);
    float sq = wave_sum(x2.x * x2.x + x2.y * x2.y);
    float mu = s * (1.f / 96.f);
    float var = sq * (1.f / 96.f) - mu * mu;
    float rs = rsqrtf(var + 1e-5f);
    float p = 0.f;
    if (act) {
        float2 g2 = *(const float2*)(g + d);
        float2 b2 = *(const float2*)(bt + d);
        float2 w2 = *(const float2*)(fcW + d);
        float y0 = fmaxf((x2.x - mu) * rs * g2.x + b2.x, 0.f);
        float y1 = fmaxf((x2.y - mu) * rs * g2.y + b2.y, 0.f);
        p = y0 * w2.x + y1 * w2.y;
    }
    p = wave_sum(p);
    if (lane == 0) out[node] = p + fcb[0];
}

extern "C" void kernel_launch(void* const* d_in, const int* in_sizes, int n_in,
                              void* d_out, int out_size, void* d_ws, size_t ws_size,
                              hipStream_t stream) {
    const float* x    = (const float*)d_in[0];
    const int*   ei   = (const int*)  d_in[1];
    const float* ew   = (const float*)d_in[2];
    const float* encW = (const float*)d_in[3];
    const float* encB = (const float*)d_in[4];
    const float* Wl   = (const float*)d_in[5];
    const float* bl   = (const float*)d_in[6];
    const float* Wr   = (const float*)d_in[7];
    const float* br   = (const float*)d_in[8];
    const float* We   = (const float*)d_in[9];
    const float* att  = (const float*)d_in[10];
    const float* bias = (const float*)d_in[11];
    const float* lng  = (const float*)d_in[12];
    const float* lnb  = (const float*)d_in[13];
    const float* lnfg = (const float*)d_in[14];
    const float* lnfb = (const float*)d_in[15];
    const float* fcW  = (const float*)d_in[16];
    const float* fcb  = (const float*)d_in[17];
    float* out = (float*)d_out;

    const int* src = ei;
    const int* dst = ei + EE;

    char* ws = (char*)d_ws;
    size_t off = 0;
    auto alloc = [&](size_t bytes) -> void* {
        void* p = ws + off;
        off += (bytes + 255) & ~(size_t)255;
        return p;
    };
    float* h      = (float*)alloc((size_t)NN * HID * 4);
    float* hn     = (float*)alloc((size_t)NN * HID * 4);
    float* xl     = (float*)alloc((size_t)NN * HID * 4);
    float* xr     = (float*)alloc((size_t)NN * HID * 4);
    int*   deg    = (int*)  alloc((size_t)NN * 4);
    int*   rowptr = (int*)  alloc((size_t)(NN + 1) * 4);
    int*   cursor = (int*)  alloc((size_t)NN * 4);
    int*   srcs   = (int*)  alloc((size_t)EE * 4);
    float* ews    = (float*)alloc((size_t)EE * 4);
    int*   parts  = (int*)  alloc(256 * 4);

    const int NB = (NN + CHUNK - 1) / CHUNK;   // 49
    const int EB = (EE + 255) / 256;           // 3125
    const int GB = (NN + 31) / 32;             // 1563
    const int WB = (NN + 3) / 4;               // 12500

    // CSR build (payload-reordered)
    hipMemsetAsync(deg, 0, (size_t)NN * 4, stream);
    k_hist<<<EB, 256, 0, stream>>>(dst, deg, EE);
    k_scan1<<<NB, 256, 0, stream>>>(deg, parts, NN);
    k_scan_mid<<<1, 1, 0, stream>>>(parts, NB, rowptr, NN);
    k_scan3<<<NB, 256, 0, stream>>>(deg, parts, rowptr, cursor, NN);
    k_scatter<<<EB, 256, 0, stream>>>(src, dst, ew, cursor, srcs, ews, EE);

    // encoder
    k_enc<<<GB, 192, 0, stream>>>(x, encW, encB, h, NN);

    for (int l = 0; l < NL; l++) {
        k_ln_relu<<<WB, 256, 0, stream>>>(h, lng + l * HID, lnb + l * HID, hn, NN);
        k_gemm2<<<GB, 192, 0, stream>>>(hn, Wl + l * HID * HID, bl + l * HID,
                                        Wr + l * HID * HID, br + l * HID, xl, xr, NN);
        k_gat<<<WB, 256, 0, stream>>>(xl, xr, srcs, ews, rowptr,
                                      We + l * HID, att + l * HID, bias + l * HID, h, NN);
    }

    k_final<<<WB, 256, 0, stream>>>(h, lnfg, lnfb, fcW, fcb, out, NN);
}

// Round 3
// 632.168 us; speedup vs baseline: 1.8816x; 1.2995x over previous
//
#include <hip/hip_runtime.h>
#include <math.h>

#define NN 50000
#define EE 800000
#define FIN 128
#define HID 96
#define NL 4
#define CHUNK 1024

__device__ __forceinline__ float wave_sum(float v) {
    #pragma unroll
    for (int off = 32; off > 0; off >>= 1) v += __shfl_xor(v, off);
    return v;
}

// ---------------- CSR build ----------------
__global__ void k_hist(const int* __restrict__ dst, int* __restrict__ deg, int E) {
    int e = blockIdx.x * blockDim.x + threadIdx.x;
    if (e < E) atomicAdd(&deg[dst[e]], 1);
}

__global__ void k_scan1(const int* __restrict__ deg, int* __restrict__ partials, int n) {
    __shared__ int lds[256];
    int t = threadIdx.x;
    int base = blockIdx.x * CHUNK + t * 4;
    int s = 0;
    #pragma unroll
    for (int q = 0; q < 4; q++) { int idx = base + q; if (idx < n) s += deg[idx]; }
    lds[t] = s; __syncthreads();
    for (int o = 128; o > 0; o >>= 1) { if (t < o) lds[t] += lds[t + o]; __syncthreads(); }
    if (t == 0) partials[blockIdx.x] = lds[0];
}

__global__ void k_scan_mid(int* partials, int nb, int* rowptr, int n) {
    int run = 0;
    for (int i = 0; i < nb; i++) { int v = partials[i]; partials[i] = run; run += v; }
    rowptr[n] = run;
}

__global__ void k_scan3(const int* __restrict__ deg, const int* __restrict__ partials,
                        int* __restrict__ rowptr, int* __restrict__ cursor, int n) {
    __shared__ int lds[256];
    int t = threadIdx.x;
    int base = blockIdx.x * CHUNK + t * 4;
    int v[4];
    #pragma unroll
    for (int q = 0; q < 4; q++) { int idx = base + q; v[q] = (idx < n) ? deg[idx] : 0; }
    int tsum = v[0] + v[1] + v[2] + v[3];
    lds[t] = tsum; __syncthreads();
    for (int o = 1; o < 256; o <<= 1) {
        int add = (t >= o) ? lds[t - o] : 0;
        __syncthreads();
        lds[t] += add;
        __syncthreads();
    }
    int excl = lds[t] - tsum;
    int run = partials[blockIdx.x] + excl;
    #pragma unroll
    for (int q = 0; q < 4; q++) {
        int idx = base + q;
        if (idx < n) { rowptr[idx] = run; cursor[idx] = run; run += v[q]; }
    }
}

__global__ void k_scatter(const int* __restrict__ src, const int* __restrict__ dst,
                          const float* __restrict__ ew, int* __restrict__ cursor,
                          int* __restrict__ srcs_o, float* __restrict__ ews_o, int E) {
    int e = blockIdx.x * blockDim.x + threadIdx.x;
    if (e < E) {
        int p = atomicAdd(&cursor[dst[e]], 1);
        srcs_o[p] = src[e];
        ews_o[p]  = ew[e];
    }
}

// ---------------- encoder GEMM: h = x @ W + b  (50000x128 @ 128x96) ----------------
__global__ __launch_bounds__(192) void k_enc(const float* __restrict__ x, const float* __restrict__ W,
                                             const float* __restrict__ b, float* __restrict__ h, int n) {
    __shared__ float xs[32 * 129];
    __shared__ float ws[32 * 100];
    int t = threadIdx.x;
    int i0 = blockIdx.x * 32;
    for (int u = t; u < 32 * 32; u += 192) {
        int r = u >> 5, q = u & 31;
        int row = i0 + r;
        float4 v = make_float4(0.f, 0.f, 0.f, 0.f);
        if (row < n) v = *(const float4*)(x + (size_t)row * FIN + 4 * q);
        float* d = xs + r * 129 + 4 * q;
        d[0] = v.x; d[1] = v.y; d[2] = v.z; d[3] = v.w;
    }
    int cg = t % 24, rg = t / 24;
    int c0 = 4 * cg, r0 = 4 * rg;
    float acc[4][4];
    #pragma unroll
    for (int i = 0; i < 4; i++)
        #pragma unroll
        for (int j = 0; j < 4; j++) acc[i][j] = 0.f;
    for (int kt = 0; kt < FIN; kt += 32) {
        __syncthreads();
        for (int u = t; u < 32 * 24; u += 192) {
            int kk = u / 24, q = u % 24;
            float4 v = *(const float4*)(W + (size_t)(kt + kk) * 96 + 4 * q);
            float* d = ws + kk * 100 + 4 * q;
            d[0] = v.x; d[1] = v.y; d[2] = v.z; d[3] = v.w;
        }
        __syncthreads();
        #pragma unroll 8
        for (int kk = 0; kk < 32; kk++) {
            float hv[4];
            #pragma unroll
            for (int i = 0; i < 4; i++) hv[i] = xs[(r0 + i) * 129 + kt + kk];
            float4 w4 = *(const float4*)(ws + kk * 100 + c0);
            #pragma unroll
            for (int i = 0; i < 4; i++) {
                acc[i][0] = fmaf(hv[i], w4.x, acc[i][0]);
                acc[i][1] = fmaf(hv[i], w4.y, acc[i][1]);
                acc[i][2] = fmaf(hv[i], w4.z, acc[i][2]);
                acc[i][3] = fmaf(hv[i], w4.w, acc[i][3]);
            }
        }
    }
    float4 b4 = *(const float4*)(b + c0);
    #pragma unroll
    for (int i = 0; i < 4; i++) {
        int row = i0 + r0 + i;
        if (row < n) {
            float4 o = make_float4(acc[i][0] + b4.x, acc[i][1] + b4.y,
                                   acc[i][2] + b4.z, acc[i][3] + b4.w);
            *(float4*)(h + (size_t)row * HID + c0) = o;
        }
    }
}

// ---------------- layer GEMMs: xl = hn@Wl+bl, xr = hn@Wr+br ----------------
__global__ __launch_bounds__(192) void k_gemm2(const float* __restrict__ hn,
        const float* __restrict__ Wl, const float* __restrict__ bl,
        const float* __restrict__ Wr, const float* __restrict__ br,
        float* __restrict__ xl, float* __restrict__ xr, int n) {
    __shared__ float hs[32 * 97];
    __shared__ float wsl[32 * 100];
    __shared__ float wsr[32 * 100];
    int t = threadIdx.x;
    int i0 = blockIdx.x * 32;
    for (int u = t; u < 32 * 24; u += 192) {
        int r = u / 24, q = u % 24;
        int row = i0 + r;
        float4 v = make_float4(0.f, 0.f, 0.f, 0.f);
        if (row < n) v = *(const float4*)(hn + (size_t)row * HID + 4 * q);
        float* d = hs + r * 97 + 4 * q;
        d[0] = v.x; d[1] = v.y; d[2] = v.z; d[3] = v.w;
    }
    int cg = t % 24, rg = t / 24;
    int c0 = 4 * cg, r0 = 4 * rg;
    float accl[4][4], accr[4][4];
    #pragma unroll
    for (int i = 0; i < 4; i++)
        #pragma unroll
        for (int j = 0; j < 4; j++) { accl[i][j] = 0.f; accr[i][j] = 0.f; }
    for (int kt = 0; kt < HID; kt += 32) {
        __syncthreads();
        for (int u = t; u < 32 * 24; u += 192) {
            int kk = u / 24, q = u % 24;
            float4 vl = *(const float4*)(Wl + (size_t)(kt + kk) * 96 + 4 * q);
            float4 vr = *(const float4*)(Wr + (size_t)(kt + kk) * 96 + 4 * q);
            float* dl = wsl + kk * 100 + 4 * q;
            float* dr = wsr + kk * 100 + 4 * q;
            dl[0] = vl.x; dl[1] = vl.y; dl[2] = vl.z; dl[3] = vl.w;
            dr[0] = vr.x; dr[1] = vr.y; dr[2] = vr.z; dr[3] = vr.w;
        }
        __syncthreads();
        #pragma unroll 4
        for (int kk = 0; kk < 32; kk++) {
            float hv[4];
            #pragma unroll
            for (int i = 0; i < 4; i++) hv[i] = hs[(r0 + i) * 97 + kt + kk];
            float4 wl4 = *(const float4*)(wsl + kk * 100 + c0);
            float4 wr4 = *(const float4*)(wsr + kk * 100 + c0);
            #pragma unroll
            for (int i = 0; i < 4; i++) {
                accl[i][0] = fmaf(hv[i], wl4.x, accl[i][0]);
                accl[i][1] = fmaf(hv[i], wl4.y, accl[i][1]);
                accl[i][2] = fmaf(hv[i], wl4.z, accl[i][2]);
                accl[i][3] = fmaf(hv[i], wl4.w, accl[i][3]);
                accr[i][0] = fmaf(hv[i], wr4.x, accr[i][0]);
                accr[i][1] = fmaf(hv[i], wr4.y, accr[i][1]);
                accr[i][2] = fmaf(hv[i], wr4.z, accr[i][2]);
                accr[i][3] = fmaf(hv[i], wr4.w, accr[i][3]);
            }
        }
    }
    float4 bl4 = *(const float4*)(bl + c0);
    float4 br4 = *(const float4*)(br + c0);
    #pragma unroll
    for (int i = 0; i < 4; i++) {
        int row = i0 + r0 + i;
        if (row < n) {
            float4 ol = make_float4(accl[i][0] + bl4.x, accl[i][1] + bl4.y,
                                    accl[i][2] + bl4.z, accl[i][3] + bl4.w);
            float4 orr = make_float4(accr[i][0] + br4.x, accr[i][1] + br4.y,
                                     accr[i][2] + br4.z, accr[i][3] + br4.w);
            *(float4*)(xl + (size_t)row * HID + c0) = ol;
            *(float4*)(xr + (size_t)row * HID + c0) = orr;
        }
    }
}

// ---------------- LN + relu (post-encoder only) ----------------
__global__ __launch_bounds__(256) void k_ln_relu(const float* __restrict__ h, const float* __restrict__ g,
                                                 const float* __restrict__ bt, float* __restrict__ hn, int n) {
    int lane = threadIdx.x & 63;
    int node = blockIdx.x * 4 + (threadIdx.x >> 6);
    if (node >= n) return;
    bool act = lane < 48;
    int d = lane * 2;
    float2 x2 = make_float2(0.f, 0.f);
    if (act) x2 = *(const float2*)(h + (size_t)node * HID + d);
    float s  = wave_sum(x2.x + x2.y);
    float sq = wave_sum(x2.x * x2.x + x2.y * x2.y);
    float mu = s * (1.f / 96.f);
    float var = sq * (1.f / 96.f) - mu * mu;
    float rs = rsqrtf(var + 1e-5f);
    if (act) {
        float2 g2 = *(const float2*)(g + d);
        float2 b2 = *(const float2*)(bt + d);
        float2 o;
        o.x = fmaxf((x2.x - mu) * rs * g2.x + b2.x, 0.f);
        o.y = fmaxf((x2.y - mu) * rs * g2.y + b2.y, 0.f);
        *(float2*)(hn + (size_t)node * HID + d) = o;
    }
}

// ---------------- fused GATv2 + residual + next-layer LN (or final LN+fc) ----------------
// wave = 1 node; 4 groups of 16 lanes process 4 edges/iter; lane owns dims [6*sub, 6*sub+6)
// mode 0: write h (residual) and hn = relu(LN(h)) for next layer
// mode 1: write out = relu(LN(h)) @ fcW + fcb   (h not written)
__global__ __launch_bounds__(256) void k_gat_fused(const float* __restrict__ xl, const float* __restrict__ xr,
        const int* __restrict__ srcs, const float* __restrict__ ews,
        const int* __restrict__ rowptr,
        const float* __restrict__ We, const float* __restrict__ att, const float* __restrict__ bias,
        float* __restrict__ h, float* __restrict__ hn_or_out,
        const float* __restrict__ g, const float* __restrict__ bt,
        const float* __restrict__ fcW, const float* __restrict__ fcb,
        int mode, int n) {
    int lane = threadIdx.x & 63;
    int node = blockIdx.x * 4 + (threadIdx.x >> 6);
    if (node >= n) return;
    int grp = lane >> 4, sub = lane & 15;
    int d0 = sub * 6;

    float we[6], at[6], xrv[6];
    #pragma unroll
    for (int j = 0; j < 3; j++) {
        float2 a = *(const float2*)(We + d0 + 2 * j);  we[2*j] = a.x;  we[2*j+1] = a.y;
        float2 c = *(const float2*)(att + d0 + 2 * j); at[2*j] = c.x;  at[2*j+1] = c.y;
        float2 r = *(const float2*)(xr + (size_t)node * HID + d0 + 2 * j);
        xrv[2*j] = r.x; xrv[2*j+1] = r.y;
    }

    int beg = rowptr[node], end = rowptr[node + 1];
    float m = -INFINITY, ssum = 0.f;
    float acc[6];
    #pragma unroll
    for (int j = 0; j < 6; j++) acc[j] = 0.f;

    auto load_quad = [&](int p, float& w, bool& val, float* v) {
        int pe = p + grp;
        val = pe < end;
        int pc = val ? pe : end - 1;
        int s = srcs[pc];
        w = ews[pc];
        const float* vp = xl + (size_t)s * HID + d0;
        #pragma unroll
        for (int j = 0; j < 3; j++) {
            float2 a = *(const float2*)(vp + 2 * j);
            v[2*j] = a.x; v[2*j+1] = a.y;
        }
    };
    auto process = [&](float w, bool val, const float* v) {
        float q = 0.f;
        #pragma unroll
        for (int j = 0; j < 6; j++) {
            float t = v[j] + xrv[j] + w * we[j];
            t = (t > 0.f ? t : 0.2f * t);
            q = fmaf(t, at[j], q);
        }
        q += __shfl_xor(q, 1); q += __shfl_xor(q, 2);
        q += __shfl_xor(q, 4); q += __shfl_xor(q, 8);
        if (!val) q = -INFINITY;
        float amax = fmaxf(q, __shfl_xor(q, 16));
        amax = fmaxf(amax, __shfl_xor(amax, 32));
        float mn = fmaxf(m, amax);
        float sc = __expf(m - mn);
        float e = val ? __expf(q - mn) : 0.f;
        ssum = ssum * sc + e;
        #pragma unroll
        for (int j = 0; j < 6; j++) acc[j] = fmaf(acc[j], sc, e * v[j]);
        m = mn;
    };

    if (beg < end) {
        float wA; bool vA; float vvA[6];
        load_quad(beg, wA, vA, vvA);
        for (int p = beg; p < end; p += 4) {
            int pn = p + 4;
            float wB = 0.f; bool vB = false; float vvB[6] = {0,0,0,0,0,0};
            if (pn < end) load_quad(pn, wB, vB, vvB);
            process(wA, vA, vvA);
            wA = wB; vA = vB;
            #pragma unroll
            for (int j = 0; j < 6; j++) vvA[j] = vvB[j];
        }
    }

    // cross-group combine
    ssum += __shfl_xor(ssum, 16); ssum += __shfl_xor(ssum, 32);
    #pragma unroll
    for (int j = 0; j < 6; j++) {
        acc[j] += __shfl_xor(acc[j], 16);
        acc[j] += __shfl_xor(acc[j], 32);
    }
    float inv = 1.f / (ssum + 1e-16f);

    // residual row update
    float nh[6];
    #pragma unroll
    for (int j = 0; j < 3; j++) {
        float2 hv = *(const float2*)(h + (size_t)node * HID + d0 + 2 * j);
        float2 b2 = *(const float2*)(bias + d0 + 2 * j);
        nh[2*j]   = hv.x + acc[2*j]   * inv + b2.x;
        nh[2*j+1] = hv.y + acc[2*j+1] * inv + b2.y;
    }

    // LN over row (all groups hold identical totals; width-16 reduce)
    float s1 = 0.f, s2 = 0.f;
    #pragma unroll
    for (int j = 0; j < 6; j++) { s1 += nh[j]; s2 += nh[j] * nh[j]; }
    #pragma unroll
    for (int off = 1; off < 16; off <<= 1) {
        s1 += __shfl_xor(s1, off);
        s2 += __shfl_xor(s2, off);
    }
    float mu = s1 * (1.f / 96.f);
    float var = s2 * (1.f / 96.f) - mu * mu;
    float rs = rsqrtf(var + 1e-5f);

    if (mode == 0) {
        if (grp == 0) {
            #pragma unroll
            for (int j = 0; j < 3; j++) {
                float2 g2 = *(const float2*)(g + d0 + 2 * j);
                float2 b2 = *(const float2*)(bt + d0 + 2 * j);
                float2 o;
                o.x = fmaxf((nh[2*j]   - mu) * rs * g2.x + b2.x, 0.f);
                o.y = fmaxf((nh[2*j+1] - mu) * rs * g2.y + b2.y, 0.f);
                *(float2*)(h + (size_t)node * HID + d0 + 2 * j) = make_float2(nh[2*j], nh[2*j+1]);
                *(float2*)(hn_or_out + (size_t)node * HID + d0 + 2 * j) = o;
            }
        }
    } else {
        float pacc = 0.f;
        #pragma unroll
        for (int j = 0; j < 3; j++) {
            float2 g2 = *(const float2*)(g + d0 + 2 * j);
            float2 b2 = *(const float2*)(bt + d0 + 2 * j);
            float2 w2 = *(const float2*)(fcW + d0 + 2 * j);
            float y0 = fmaxf((nh[2*j]   - mu) * rs * g2.x + b2.x, 0.f);
            float y1 = fmaxf((nh[2*j+1] - mu) * rs * g2.y + b2.y, 0.f);
            pacc += y0 * w2.x + y1 * w2.y;
        }
        #pragma unroll
        for (int off = 1; off < 16; off <<= 1) pacc += __shfl_xor(pacc, off);
        if (lane == 0) hn_or_out[node] = pacc + fcb[0];
    }
}

extern "C" void kernel_launch(void* const* d_in, const int* in_sizes, int n_in,
                              void* d_out, int out_size, void* d_ws, size_t ws_size,
                              hipStream_t stream) {
    const float* x    = (const float*)d_in[0];
    const int*   ei   = (const int*)  d_in[1];
    const float* ew   = (const float*)d_in[2];
    const float* encW = (const float*)d_in[3];
    const float* encB = (const float*)d_in[4];
    const float* Wl   = (const float*)d_in[5];
    const float* bl   = (const float*)d_in[6];
    const float* Wr   = (const float*)d_in[7];
    const float* br   = (const float*)d_in[8];
    const float* We   = (const float*)d_in[9];
    const float* att  = (const float*)d_in[10];
    const float* bias = (const float*)d_in[11];
    const float* lng  = (const float*)d_in[12];
    const float* lnb  = (const float*)d_in[13];
    const float* lnfg = (const float*)d_in[14];
    const float* lnfb = (const float*)d_in[15];
    const float* fcW  = (const float*)d_in[16];
    const float* fcb  = (const float*)d_in[17];
    float* out = (float*)d_out;

    const int* src = ei;
    const int* dst = ei + EE;

    char* ws = (char*)d_ws;
    size_t off = 0;
    auto alloc = [&](size_t bytes) -> void* {
        void* p = ws + off;
        off += (bytes + 255) & ~(size_t)255;
        return p;
    };
    float* h      = (float*)alloc((size_t)NN * HID * 4);
    float* hn     = (float*)alloc((size_t)NN * HID * 4);
    float* xl     = (float*)alloc((size_t)NN * HID * 4);
    float* xr     = (float*)alloc((size_t)NN * HID * 4);
    int*   deg    = (int*)  alloc((size_t)NN * 4);
    int*   rowptr = (int*)  alloc((size_t)(NN + 1) * 4);
    int*   cursor = (int*)  alloc((size_t)NN * 4);
    int*   srcs   = (int*)  alloc((size_t)EE * 4);
    float* ews    = (float*)alloc((size_t)EE * 4);
    int*   parts  = (int*)  alloc(256 * 4);

    const int NB = (NN + CHUNK - 1) / CHUNK;   // 49
    const int EB = (EE + 255) / 256;           // 3125
    const int GB = (NN + 31) / 32;             // 1563
    const int WB = (NN + 3) / 4;               // 12500

    // CSR build (payload-reordered)
    hipMemsetAsync(deg, 0, (size_t)NN * 4, stream);
    k_hist<<<EB, 256, 0, stream>>>(dst, deg, EE);
    k_scan1<<<NB, 256, 0, stream>>>(deg, parts, NN);
    k_scan_mid<<<1, 1, 0, stream>>>(parts, NB, rowptr, NN);
    k_scan3<<<NB, 256, 0, stream>>>(deg, parts, rowptr, cursor, NN);
    k_scatter<<<EB, 256, 0, stream>>>(src, dst, ew, cursor, srcs, ews, EE);

    // encoder + first LN
    k_enc<<<GB, 192, 0, stream>>>(x, encW, encB, h, NN);
    k_ln_relu<<<WB, 256, 0, stream>>>(h, lng, lnb, hn, NN);

    for (int l = 0; l < NL; l++) {
        k_gemm2<<<GB, 192, 0, stream>>>(hn, Wl + l * HID * HID, bl + l * HID,
                                        Wr + l * HID * HID, br + l * HID, xl, xr, NN);
        if (l < NL - 1) {
            // epilogue produces hn for layer l+1 (LN params l+1)
            k_gat_fused<<<WB, 256, 0, stream>>>(xl, xr, srcs, ews, rowptr,
                We + l * HID, att + l * HID, bias + l * HID,
                h, hn, lng + (l + 1) * HID, lnb + (l + 1) * HID,
                (const float*)nullptr, (const float*)nullptr, 0, NN);
        } else {
            // final: LN_f + relu + fc -> out
            k_gat_fused<<<WB, 256, 0, stream>>>(xl, xr, srcs, ews, rowptr,
                We + l * HID, att + l * HID, bias + l * HID,
                h, out, lnfg, lnfb, fcW, fcb, 1, NN);
        }
    }
}